// Round 13
// baseline (148.135 us; speedup 1.0000x reference)
//
#include <hip/hip_runtime.h>

#define NN 100000
#define NE 1600000
#define IN_DIM 16
#define MSG_DIM 128
#define DT_C 0.1f
#define EPS_C 1e-8f
#define BKT 128                          // dst-nodes per bucket
#define NB ((NN + BKT - 1) / BKT)        // 782 buckets
#define EPB 2560                         // edges per bucketing block
#define NBB (NE / EPB)                   // 625 (exact)
#define EPT (EPB / 256)                  // 10 edges per thread
#define CAPB 4096                        // padded bucket region (mean 2048, 45 sigma)
#define CAP 2560                         // LDS csr-slice capacity in bucket2csr

__device__ __forceinline__ float blo(unsigned c) { return __uint_as_float(c << 16); }
__device__ __forceinline__ float bhi(unsigned c) { return __uint_as_float(c & 0xFFFF0000u); }
__device__ __forceinline__ unsigned short f2b(float f) {
    unsigned int i = __float_as_uint(f);
    unsigned int b = i + 0x7FFFu + ((i >> 16) & 1u);   // round-nearest-even
    return (unsigned short)(b >> 16);
}

// Wc = W_msg @ W_out (16x16), bc = b_msg @ W_out (16)
__global__ void compute_wc_kernel(const float* __restrict__ W_msg,
                                  const float* __restrict__ b_msg,
                                  const float* __restrict__ W_out,
                                  float* __restrict__ Wc,
                                  float* __restrict__ bc) {
    int t = threadIdx.x;            // 256 threads
    int i = t >> 4, j = t & 15;
    float s = 0.f;
    for (int k = 0; k < MSG_DIM; ++k)
        s += W_msg[i * MSG_DIM + k] * W_out[k * IN_DIM + j];
    Wc[t] = s;
    if (t < IN_DIM) {
        float sb = 0.f;
        for (int k = 0; k < MSG_DIM; ++k)
            sb += b_msg[k] * W_out[k * IN_DIM + t];
        bc[t] = sb;
    }
}

// f32 state -> bf16 shadow (pair: low16 = even dim, high16 = odd dim).
// Also initializes gcur (padded bucket bases) -- saves a launch.
__global__ void cvt_kernel(const float* __restrict__ x, unsigned* __restrict__ xb,
                           int* __restrict__ gcur) {
    int i = blockIdx.x * blockDim.x + threadIdx.x;      // pair index
    if (i < NB) gcur[i] = i * CAPB;
    if (i * 2 >= NN * IN_DIM) return;
    float2 v = ((const float2*)x)[i];
    xb[i] = (unsigned)f2b(v.x) | ((unsigned)f2b(v.y) << 16);
}

// Bucketing pass into padded regions: partition edges by dst-bucket as packed
// (d_local<<17 | src). LDS per-bucket count, one global reserve atomic per
// (block,bucket), contiguous runs -> coalesced single edge-pass.
__global__ __launch_bounds__(256) void bucketA_kernel(const int* __restrict__ src,
                                                      const int* __restrict__ dst,
                                                      int* __restrict__ gcur,
                                                      unsigned* __restrict__ bucket) {
    __shared__ int lcnt[NB];
    __shared__ int lbase[NB];
    int t = threadIdx.x;
    for (int j = t; j < NB; j += 256) lcnt[j] = 0;
    __syncthreads();

    int d[EPT], s[EPT];
    int base = blockIdx.x * EPB + t;
    #pragma unroll
    for (int it = 0; it < EPT; ++it) {
        d[it] = dst[base + it * 256];
        s[it] = src[base + it * 256];
    }
    #pragma unroll
    for (int it = 0; it < EPT; ++it) atomicAdd(&lcnt[d[it] >> 7], 1);
    __syncthreads();
    for (int j = t; j < NB; j += 256) {
        int c = lcnt[j];
        lbase[j] = c ? atomicAdd(&gcur[j], c) : 0;
        lcnt[j] = 0;                // reuse as local cursor
    }
    __syncthreads();
    #pragma unroll
    for (int it = 0; it < EPT; ++it) {
        int b = d[it] >> 7;
        int slot = atomicAdd(&lcnt[b], 1);
        bucket[lbase[b] + slot] = ((unsigned)(d[it] & 127) << 17) | (unsigned)s[it];
    }
}

// Exclusive scan of filled counts (gcur[b]-b*CAPB) -> compact bases gbase.
__global__ __launch_bounds__(1024) void scan782_kernel(const int* __restrict__ gcur,
                                                       int* __restrict__ gbase,
                                                       int* __restrict__ offs) {
    __shared__ int sh[1024];
    int t = threadIdx.x;
    int v = (t < NB) ? (gcur[t] - t * CAPB) : 0;
    sh[t] = v;
    __syncthreads();
    #pragma unroll
    for (int off = 1; off < 1024; off <<= 1) {
        int u = (t >= off) ? sh[t - off] : 0;
        __syncthreads();
        sh[t] += u;
        __syncthreads();
    }
    if (t < NB) gbase[t] = sh[t] - v;
    if (t == 0) { gbase[NB] = NE; offs[NN] = NE; }
}

// Padded bucket slice -> node-ordered compact CSR, one block per bucket.
// Scatter confined to a 10KB LDS window; csr/offs written coalesced.
__global__ __launch_bounds__(256) void bucket2csr_kernel(const unsigned* __restrict__ bucket,
                                                         const int* __restrict__ gcur,
                                                         const int* __restrict__ gbase,
                                                         int* __restrict__ offs,
                                                         int* __restrict__ csr) {
    __shared__ int lcnt[BKT];
    __shared__ int ls[BKT];
    __shared__ int lcur[BKT];
    __shared__ int lcsr[CAP];
    int b = blockIdx.x;
    int t = threadIdx.x;
    int p0 = b * CAPB;                  // padded read base
    int len = gcur[b] - p0;             // filled count
    int g0 = gbase[b];                  // compact write base
    if (t < BKT) lcnt[t] = 0;
    __syncthreads();
    for (int i = t; i < len; i += 256)
        atomicAdd(&lcnt[bucket[p0 + i] >> 17], 1);
    __syncthreads();
    if (t < BKT) ls[t] = lcnt[t];
    __syncthreads();
    #pragma unroll
    for (int off = 1; off < BKT; off <<= 1) {
        int u = (t < BKT && t >= off) ? ls[t - off] : 0;
        __syncthreads();
        if (t < BKT) ls[t] += u;
        __syncthreads();
    }
    if (t < BKT) {
        int ex = ls[t] - lcnt[t];       // exclusive, slice-local
        lcur[t] = ex;
        int n = b * BKT + t;
        if (n < NN) offs[n] = g0 + ex;
    }
    __syncthreads();
    if (len <= CAP) {
        for (int i = t; i < len; i += 256) {
            unsigned pk = bucket[p0 + i];
            int pos = atomicAdd(&lcur[pk >> 17], 1);
            lcsr[pos] = (int)(pk & 0x1FFFFu);
        }
        __syncthreads();
        for (int i = t; i < len; i += 256) csr[g0 + i] = lcsr[i];
    } else {                             // statistically unreachable guard
        for (int i = t; i < len; i += 256) {
            unsigned pk = bucket[p0 + i];
            int pos = atomicAdd(&lcur[pk >> 17], 1);
            csr[g0 + pos] = (int)(pk & 0x1FFFFu);
        }
    }
}

// Fused per-step kernel: 16 threads per node = 8 edge-pairs x 2 row-halves.
// Each lane: ONE 16B gather per assigned edge (serial chain ~ceil(maxdeg/8)).
// Merge pairs via shfl 2,4,8; exchange halves via shfl 1; per-lane 1 output
// column of the 16x16 matvec; Euler + pol renorm (cols 3..6) + stores.
// xin != xout required (gather reads neighbor rows).
__global__ __launch_bounds__(256) void step_kernel(const float* __restrict__ xin,
                                                   const uint4* __restrict__ xbin,
                                                   const int* __restrict__ offs,
                                                   const int* __restrict__ csr,
                                                   const float* __restrict__ Wc,
                                                   const float* __restrict__ bc,
                                                   const float* __restrict__ b_out,
                                                   float* __restrict__ xout,
                                                   unsigned short* __restrict__ xbout) {
    __shared__ float sWc[256];
    __shared__ float sbc[16];
    __shared__ float sb[16];
    int t = threadIdx.x;
    sWc[t] = Wc[t];
    if (t < 16) { sbc[t] = bc[t]; sb[t] = b_out[t]; }
    __syncthreads();

    int tid = blockIdx.x * 256 + t;
    int n = tid >> 4;
    int l = t & 15;                     // lane-in-node
    int p = l >> 1;                     // edge pair 0..7
    int hf = l & 1;                     // row half 0..1
    if (n >= NN) return;

    int o0 = offs[n];
    int o1 = offs[n + 1];

    float acc[8];
    #pragma unroll
    for (int j = 0; j < 8; ++j) acc[j] = 0.f;

    for (int e = o0 + p; e < o1; e += 8) {
        int s = csr[e];
        uint4 v = xbin[s * 2 + hf];     // 16B: 8 bf16 of this half-row
        acc[0] += blo(v.x); acc[1] += bhi(v.x);
        acc[2] += blo(v.y); acc[3] += bhi(v.y);
        acc[4] += blo(v.z); acc[5] += bhi(v.z);
        acc[6] += blo(v.w); acc[7] += bhi(v.w);
    }

    // sum the 8 pairs (same hf lanes differ by xor 2, 4, 8)
    #pragma unroll
    for (int j = 0; j < 8; ++j) {
        acc[j] += __shfl_xor(acc[j], 2);
        acc[j] += __shfl_xor(acc[j], 4);
        acc[j] += __shfl_xor(acc[j], 8);
    }
    // exchange halves (xor 1) -> full 16-dim aggregate, static indexing
    float a[16];
    #pragma unroll
    for (int j = 0; j < 8; ++j) {
        float oth = __shfl_xor(acc[j], 1);
        a[j]     = hf ? oth    : acc[j];
        a[8 + j] = hf ? acc[j] : oth;
    }

    float dg = (float)(o1 - o0);

    // this lane's single output column c = l
    float oc = dg * sbc[l] + sb[l];
    #pragma unroll
    for (int k = 0; k < 16; ++k)
        oc = fmaf(a[k], sWc[k * 16 + l], oc);

    float xv = xin[(size_t)n * 16 + l];
    float xn = xv + DT_C * oc;

    // pol renorm over cols 3..6 (all within lanes 0..7: butterfly over bits 0..2)
    bool inp = (l >= 3 && l <= 6);
    float ssp = inp ? xn * xn : 0.f;
    ssp += __shfl_xor(ssp, 1);
    ssp += __shfl_xor(ssp, 2);
    ssp += __shfl_xor(ssp, 4);
    float sc = 1.0f / fmaxf(sqrtf(ssp), EPS_C);
    if (inp) xn *= sc;

    xout[(size_t)n * 16 + l] = xn;
    xbout[(size_t)n * 16 + l] = f2b(xn);
}

extern "C" void kernel_launch(void* const* d_in, const int* in_sizes, int n_in,
                              void* d_out, int out_size, void* d_ws, size_t ws_size,
                              hipStream_t stream) {
    const float* x0    = (const float*)d_in[0];
    const int*   ei    = (const int*)d_in[1];   // (2, NE): row0=src, row1=dst
    const float* W_msg = (const float*)d_in[2];
    const float* b_msg = (const float*)d_in[3];
    const float* W_out = (const float*)d_in[4];
    const float* b_out = (const float*)d_in[5];

    float* X = (float*)d_out;                   // final state buffer (ping-pong B1)

    // ws layout: Y (NN*16 f), xb0/xb1 (NN*16 bf16), bucket (NB*CAPB u32,
    // padded), csr (NE), offs (NN+1), gbase (NB+1), gcur (NB), Wc, bc
    float*          Y      = (float*)d_ws;
    unsigned*       xb0    = (unsigned*)(Y + (size_t)NN * IN_DIM);      // NN*8 u32
    unsigned*       xb1    = xb0 + (size_t)NN * (IN_DIM / 2);
    unsigned*       bucket = xb1 + (size_t)NN * (IN_DIM / 2);
    int*            csr    = (int*)(bucket + (size_t)NB * CAPB);
    int*            offs   = csr + NE;          // NN+1
    int*            gbase  = offs + NN + 1;     // NB+1
    int*            gcur   = gbase + NB + 1;    // NB
    float*          Wc     = (float*)(gcur + NB);
    float*          bc     = Wc + 256;

    const int* src = ei;
    const int* dst = ei + NE;

    compute_wc_kernel<<<1, 256, 0, stream>>>(W_msg, b_msg, W_out, Wc, bc);
    cvt_kernel<<<(NN * IN_DIM / 2 + 255) / 256, 256, 0, stream>>>(x0, xb0, gcur);
    bucketA_kernel<<<NBB, 256, 0, stream>>>(src, dst, gcur, bucket);
    scan782_kernel<<<1, 1024, 0, stream>>>(gcur, gbase, offs);
    bucket2csr_kernel<<<NB, 256, 0, stream>>>(bucket, gcur, gbase, offs, csr);

    const int step_threads = NN * 16;
    const int step_blocks = (step_threads + 255) / 256;

    // 4 steps, ping-pong fp32: x0 -> Y -> X -> Y -> X ; bf16 shadow xb0<->xb1
    const float*    fin[4]  = { x0,  Y,   X,   Y  };
    float*          fout[4] = { Y,   X,   Y,   X  };
    const unsigned* bin[4]  = { xb0, xb1, xb0, xb1 };
    unsigned*       bout[4] = { xb1, xb0, xb1, xb0 };
    for (int s = 0; s < 4; ++s) {
        step_kernel<<<step_blocks, 256, 0, stream>>>(
            fin[s], (const uint4*)bin[s], offs, csr,
            Wc, bc, b_out, fout[s], (unsigned short*)bout[s]);
    }
}

// Round 14
// 129.703 us; speedup vs baseline: 1.1421x; 1.1421x over previous
//
#include <hip/hip_runtime.h>

#define NN 100000
#define NE 1600000
#define IN_DIM 16
#define MSG_DIM 128
#define DT_C 0.1f
#define EPS_C 1e-8f
#define BKT 128                          // dst-nodes per bucket
#define NB ((NN + BKT - 1) / BKT)        // 782 buckets
#define EPB 2560                         // edges per bucketing block
#define NBB (NE / EPB)                   // 625 (exact)
#define EPT (EPB / 256)                  // 10 edges per thread
#define CAPB 4096                        // padded bucket region (mean 2048, 45 sigma)
#define CAP 2560                         // LDS csr-slice capacity in bucket2csr

__device__ __forceinline__ float blo(unsigned c) { return __uint_as_float(c << 16); }
__device__ __forceinline__ float bhi(unsigned c) { return __uint_as_float(c & 0xFFFF0000u); }
__device__ __forceinline__ unsigned short f2b(float f) {
    unsigned int i = __float_as_uint(f);
    unsigned int b = i + 0x7FFFu + ((i >> 16) & 1u);   // round-nearest-even
    return (unsigned short)(b >> 16);
}

// Wc = W_msg @ W_out (16x16), bc = b_msg @ W_out (16)
__global__ void compute_wc_kernel(const float* __restrict__ W_msg,
                                  const float* __restrict__ b_msg,
                                  const float* __restrict__ W_out,
                                  float* __restrict__ Wc,
                                  float* __restrict__ bc) {
    int t = threadIdx.x;            // 256 threads
    int i = t >> 4, j = t & 15;
    float s = 0.f;
    for (int k = 0; k < MSG_DIM; ++k)
        s += W_msg[i * MSG_DIM + k] * W_out[k * IN_DIM + j];
    Wc[t] = s;
    if (t < IN_DIM) {
        float sb = 0.f;
        for (int k = 0; k < MSG_DIM; ++k)
            sb += b_msg[k] * W_out[k * IN_DIM + t];
        bc[t] = sb;
    }
}

// f32 state -> bf16 shadow (pair: low16 = even dim, high16 = odd dim).
// Also initializes gcur (padded bucket bases) -- saves a launch.
__global__ void cvt_kernel(const float* __restrict__ x, unsigned* __restrict__ xb,
                           int* __restrict__ gcur) {
    int i = blockIdx.x * blockDim.x + threadIdx.x;      // pair index
    if (i < NB) gcur[i] = i * CAPB;
    if (i * 2 >= NN * IN_DIM) return;
    float2 v = ((const float2*)x)[i];
    xb[i] = (unsigned)f2b(v.x) | ((unsigned)f2b(v.y) << 16);
}

// Bucketing pass into padded regions: partition edges by dst-bucket as packed
// (d_local<<17 | src). LDS per-bucket count, one global reserve atomic per
// (block,bucket), contiguous runs -> coalesced single edge-pass.
__global__ __launch_bounds__(256) void bucketA_kernel(const int* __restrict__ src,
                                                      const int* __restrict__ dst,
                                                      int* __restrict__ gcur,
                                                      unsigned* __restrict__ bucket) {
    __shared__ int lcnt[NB];
    __shared__ int lbase[NB];
    int t = threadIdx.x;
    for (int j = t; j < NB; j += 256) lcnt[j] = 0;
    __syncthreads();

    int d[EPT], s[EPT];
    int base = blockIdx.x * EPB + t;
    #pragma unroll
    for (int it = 0; it < EPT; ++it) {
        d[it] = dst[base + it * 256];
        s[it] = src[base + it * 256];
    }
    #pragma unroll
    for (int it = 0; it < EPT; ++it) atomicAdd(&lcnt[d[it] >> 7], 1);
    __syncthreads();
    for (int j = t; j < NB; j += 256) {
        int c = lcnt[j];
        lbase[j] = c ? atomicAdd(&gcur[j], c) : 0;
        lcnt[j] = 0;                // reuse as local cursor
    }
    __syncthreads();
    #pragma unroll
    for (int it = 0; it < EPT; ++it) {
        int b = d[it] >> 7;
        int slot = atomicAdd(&lcnt[b], 1);
        bucket[lbase[b] + slot] = ((unsigned)(d[it] & 127) << 17) | (unsigned)s[it];
    }
}

// Exclusive scan of filled counts (gcur[b]-b*CAPB) -> compact bases gbase.
__global__ __launch_bounds__(1024) void scan782_kernel(const int* __restrict__ gcur,
                                                       int* __restrict__ gbase,
                                                       int* __restrict__ offs) {
    __shared__ int sh[1024];
    int t = threadIdx.x;
    int v = (t < NB) ? (gcur[t] - t * CAPB) : 0;
    sh[t] = v;
    __syncthreads();
    #pragma unroll
    for (int off = 1; off < 1024; off <<= 1) {
        int u = (t >= off) ? sh[t - off] : 0;
        __syncthreads();
        sh[t] += u;
        __syncthreads();
    }
    if (t < NB) gbase[t] = sh[t] - v;
    if (t == 0) { gbase[NB] = NE; offs[NN] = NE; }
}

// Padded bucket slice -> node-ordered compact CSR, one block per bucket.
// Scatter confined to a 10KB LDS window; csr/offs written coalesced.
__global__ __launch_bounds__(256) void bucket2csr_kernel(const unsigned* __restrict__ bucket,
                                                         const int* __restrict__ gcur,
                                                         const int* __restrict__ gbase,
                                                         int* __restrict__ offs,
                                                         int* __restrict__ csr) {
    __shared__ int lcnt[BKT];
    __shared__ int ls[BKT];
    __shared__ int lcur[BKT];
    __shared__ int lcsr[CAP];
    int b = blockIdx.x;
    int t = threadIdx.x;
    int p0 = b * CAPB;                  // padded read base
    int len = gcur[b] - p0;             // filled count
    int g0 = gbase[b];                  // compact write base
    if (t < BKT) lcnt[t] = 0;
    __syncthreads();
    for (int i = t; i < len; i += 256)
        atomicAdd(&lcnt[bucket[p0 + i] >> 17], 1);
    __syncthreads();
    if (t < BKT) ls[t] = lcnt[t];
    __syncthreads();
    #pragma unroll
    for (int off = 1; off < BKT; off <<= 1) {
        int u = (t < BKT && t >= off) ? ls[t - off] : 0;
        __syncthreads();
        if (t < BKT) ls[t] += u;
        __syncthreads();
    }
    if (t < BKT) {
        int ex = ls[t] - lcnt[t];       // exclusive, slice-local
        lcur[t] = ex;
        int n = b * BKT + t;
        if (n < NN) offs[n] = g0 + ex;
    }
    __syncthreads();
    if (len <= CAP) {
        for (int i = t; i < len; i += 256) {
            unsigned pk = bucket[p0 + i];
            int pos = atomicAdd(&lcur[pk >> 17], 1);
            lcsr[pos] = (int)(pk & 0x1FFFFu);
        }
        __syncthreads();
        for (int i = t; i < len; i += 256) csr[g0 + i] = lcsr[i];
    } else {                             // statistically unreachable guard
        for (int i = t; i < len; i += 256) {
            unsigned pk = bucket[p0 + i];
            int pos = atomicAdd(&lcur[pk >> 17], 1);
            csr[g0 + pos] = (int)(pk & 0x1FFFFu);
        }
    }
}

// Fused per-step kernel: 8 threads per node = 4 edge-pairs x 2 row-halves.
// Each lane: ONE 16B gather (uint4 = 8 bf16 = half a row) per edge; 2-way
// unrolled so TWO csr reads + TWO gathers are in flight per lane (MLP x2).
// Merge pairs via shfl 2,4; exchange halves via shfl 1; 2 output columns per
// lane of the 16x16 matvec; Euler + pol renorm (cols 3..6) + stores.
// xin != xout required (gather reads neighbor rows).
__global__ __launch_bounds__(256) void step_kernel(const float2* __restrict__ x2in,
                                                   const uint4* __restrict__ xbin,
                                                   const int* __restrict__ offs,
                                                   const int* __restrict__ csr,
                                                   const float* __restrict__ Wc,
                                                   const float* __restrict__ bc,
                                                   const float* __restrict__ b_out,
                                                   float2* __restrict__ x2out,
                                                   unsigned* __restrict__ xbout) {
    __shared__ float sWc[256];
    __shared__ float sbc[16];
    __shared__ float sb[16];
    int t = threadIdx.x;
    sWc[t] = Wc[t];
    if (t < 16) { sbc[t] = bc[t]; sb[t] = b_out[t]; }
    __syncthreads();

    int tid = blockIdx.x * 256 + t;
    int n = tid >> 3;
    int l = t & 7;                      // lane-in-node
    int p = l >> 1;                     // edge pair 0..3
    int hf = l & 1;                     // row half 0..1
    if (n >= NN) return;

    int o0 = offs[n];
    int o1 = offs[n + 1];

    float acc[8];
    #pragma unroll
    for (int j = 0; j < 8; ++j) acc[j] = 0.f;

    int e = o0 + p;
    // 2-way unrolled gather: both csr reads, then both 16B gathers, then adds.
    while (e + 4 < o1) {
        int s0 = csr[e];
        int s1 = csr[e + 4];
        uint4 v0 = xbin[s0 * 2 + hf];
        uint4 v1 = xbin[s1 * 2 + hf];
        acc[0] += blo(v0.x); acc[1] += bhi(v0.x);
        acc[2] += blo(v0.y); acc[3] += bhi(v0.y);
        acc[4] += blo(v0.z); acc[5] += bhi(v0.z);
        acc[6] += blo(v0.w); acc[7] += bhi(v0.w);
        acc[0] += blo(v1.x); acc[1] += bhi(v1.x);
        acc[2] += blo(v1.y); acc[3] += bhi(v1.y);
        acc[4] += blo(v1.z); acc[5] += bhi(v1.z);
        acc[6] += blo(v1.w); acc[7] += bhi(v1.w);
        e += 8;
    }
    if (e < o1) {
        int s0 = csr[e];
        uint4 v0 = xbin[s0 * 2 + hf];
        acc[0] += blo(v0.x); acc[1] += bhi(v0.x);
        acc[2] += blo(v0.y); acc[3] += bhi(v0.y);
        acc[4] += blo(v0.z); acc[5] += bhi(v0.z);
        acc[6] += blo(v0.w); acc[7] += bhi(v0.w);
    }

    // sum the 4 pairs (same hf lanes differ by xor 2, 4)
    #pragma unroll
    for (int j = 0; j < 8; ++j) {
        acc[j] += __shfl_xor(acc[j], 2);
        acc[j] += __shfl_xor(acc[j], 4);
    }
    // exchange halves (xor 1) -> full 16-dim aggregate, static indexing
    float a[16];
    #pragma unroll
    for (int j = 0; j < 8; ++j) {
        float oth = __shfl_xor(acc[j], 1);
        a[j]     = hf ? oth    : acc[j];
        a[8 + j] = hf ? acc[j] : oth;
    }

    float dg = (float)(o1 - o0);

    // this lane's 2 output columns c0=2l, c0+1
    int c0 = 2 * l;
    float o0f = dg * sbc[c0] + sb[c0];
    float o1f = dg * sbc[c0 + 1] + sb[c0 + 1];
    #pragma unroll
    for (int k = 0; k < 16; ++k) {
        float ak = a[k];
        o0f = fmaf(ak, sWc[k * 16 + c0], o0f);
        o1f = fmaf(ak, sWc[k * 16 + c0 + 1], o1f);
    }

    float2 xv = x2in[(size_t)n * 8 + l];
    float xn0 = xv.x + DT_C * o0f;
    float xn1 = xv.y + DT_C * o1f;

    // pol renorm over cols 3..6
    bool in0 = (c0 >= 3 && c0 <= 6);
    bool in1 = (c0 + 1 >= 3 && c0 + 1 <= 6);
    float ssp = (in0 ? xn0 * xn0 : 0.f) + (in1 ? xn1 * xn1 : 0.f);
    ssp += __shfl_xor(ssp, 1);
    ssp += __shfl_xor(ssp, 2);
    ssp += __shfl_xor(ssp, 4);
    float sc = 1.0f / fmaxf(sqrtf(ssp), EPS_C);
    if (in0) xn0 *= sc;
    if (in1) xn1 *= sc;

    x2out[(size_t)n * 8 + l] = make_float2(xn0, xn1);
    xbout[(size_t)n * 8 + l] = (unsigned)f2b(xn0) | ((unsigned)f2b(xn1) << 16);
}

extern "C" void kernel_launch(void* const* d_in, const int* in_sizes, int n_in,
                              void* d_out, int out_size, void* d_ws, size_t ws_size,
                              hipStream_t stream) {
    const float* x0    = (const float*)d_in[0];
    const int*   ei    = (const int*)d_in[1];   // (2, NE): row0=src, row1=dst
    const float* W_msg = (const float*)d_in[2];
    const float* b_msg = (const float*)d_in[3];
    const float* W_out = (const float*)d_in[4];
    const float* b_out = (const float*)d_in[5];

    float* X = (float*)d_out;                   // final state buffer (ping-pong B1)

    // ws layout: Y (NN*16 f), xb0/xb1 (NN*16 bf16), bucket (NB*CAPB u32,
    // padded), csr (NE), offs (NN+1), gbase (NB+1), gcur (NB), Wc, bc
    float*          Y      = (float*)d_ws;
    unsigned*       xb0    = (unsigned*)(Y + (size_t)NN * IN_DIM);      // NN*8 u32
    unsigned*       xb1    = xb0 + (size_t)NN * (IN_DIM / 2);
    unsigned*       bucket = xb1 + (size_t)NN * (IN_DIM / 2);
    int*            csr    = (int*)(bucket + (size_t)NB * CAPB);
    int*            offs   = csr + NE;          // NN+1
    int*            gbase  = offs + NN + 1;     // NB+1
    int*            gcur   = gbase + NB + 1;    // NB
    float*          Wc     = (float*)(gcur + NB);
    float*          bc     = Wc + 256;

    const int* src = ei;
    const int* dst = ei + NE;

    compute_wc_kernel<<<1, 256, 0, stream>>>(W_msg, b_msg, W_out, Wc, bc);
    cvt_kernel<<<(NN * IN_DIM / 2 + 255) / 256, 256, 0, stream>>>(x0, xb0, gcur);
    bucketA_kernel<<<NBB, 256, 0, stream>>>(src, dst, gcur, bucket);
    scan782_kernel<<<1, 1024, 0, stream>>>(gcur, gbase, offs);
    bucket2csr_kernel<<<NB, 256, 0, stream>>>(bucket, gcur, gbase, offs, csr);

    const int step_threads = NN * 8;
    const int step_blocks = (step_threads + 255) / 256;

    // 4 steps, ping-pong fp32: x0 -> Y -> X -> Y -> X ; bf16 shadow xb0<->xb1
    const float*    fin[4]  = { x0,  Y,   X,   Y  };
    float*          fout[4] = { Y,   X,   Y,   X  };
    const unsigned* bin[4]  = { xb0, xb1, xb0, xb1 };
    unsigned*       bout[4] = { xb1, xb0, xb1, xb0 };
    for (int s = 0; s < 4; ++s) {
        step_kernel<<<step_blocks, 256, 0, stream>>>(
            (const float2*)fin[s], (const uint4*)bin[s], offs, csr,
            Wc, bc, b_out, (float2*)fout[s], bout[s]);
    }
}

// Round 15
// 122.586 us; speedup vs baseline: 1.2084x; 1.0581x over previous
//
#include <hip/hip_runtime.h>

#define NN 100000
#define NE 1600000
#define IN_DIM 16
#define MSG_DIM 128
#define DT_C 0.1f
#define EPS_C 1e-8f
#define BKT 128                          // dst-nodes per bucket
#define NB ((NN + BKT - 1) / BKT)        // 782 buckets
#define EPB 2560                         // edges per bucketing block
#define NBB (NE / EPB)                   // 625 (exact)
#define EPT (EPB / 256)                  // 10 edges per thread
#define CAPB 4096                        // padded bucket region (mean 2048, 45 sigma)
#define CAP 2560                         // LDS csr-slice capacity in bucket2csr

__device__ __forceinline__ float blo(unsigned c) { return __uint_as_float(c << 16); }
__device__ __forceinline__ float bhi(unsigned c) { return __uint_as_float(c & 0xFFFF0000u); }
__device__ __forceinline__ unsigned short f2b(float f) {
    unsigned int i = __float_as_uint(f);
    unsigned int b = i + 0x7FFFu + ((i >> 16) & 1u);   // round-nearest-even
    return (unsigned short)(b >> 16);
}

// Fused init: Wc = W_msg@W_out, bc = b_msg@W_out (block 0); f32->bf16 shadow
// cvt (all blocks, grid-stride); gcur padded-base init. One launch.
__global__ void init_kernel(const float* __restrict__ W_msg,
                            const float* __restrict__ b_msg,
                            const float* __restrict__ W_out,
                            const float* __restrict__ x,
                            float* __restrict__ Wc,
                            float* __restrict__ bc,
                            unsigned* __restrict__ xb,
                            int* __restrict__ gcur) {
    int t = threadIdx.x;
    if (blockIdx.x == 0) {
        int i = t >> 4, j = t & 15;
        float s = 0.f;
        for (int k = 0; k < MSG_DIM; ++k)
            s += W_msg[i * MSG_DIM + k] * W_out[k * IN_DIM + j];
        Wc[t] = s;
        if (t < IN_DIM) {
            float sb = 0.f;
            for (int k = 0; k < MSG_DIM; ++k)
                sb += b_msg[k] * W_out[k * IN_DIM + t];
            bc[t] = sb;
        }
    }
    int i = blockIdx.x * blockDim.x + t;
    if (i < NB) gcur[i] = i * CAPB;
    if (i * 2 < NN * IN_DIM) {
        float2 v = ((const float2*)x)[i];
        xb[i] = (unsigned)f2b(v.x) | ((unsigned)f2b(v.y) << 16);
    }
}

// Bucketing pass into padded regions: partition edges by dst-bucket as packed
// (d_local<<17 | src). LDS per-bucket count, one global reserve atomic per
// (block,bucket), contiguous runs -> coalesced single edge-pass.
__global__ __launch_bounds__(256) void bucketA_kernel(const int* __restrict__ src,
                                                      const int* __restrict__ dst,
                                                      int* __restrict__ gcur,
                                                      unsigned* __restrict__ bucket) {
    __shared__ int lcnt[NB];
    __shared__ int lbase[NB];
    int t = threadIdx.x;
    for (int j = t; j < NB; j += 256) lcnt[j] = 0;
    __syncthreads();

    int d[EPT], s[EPT];
    int base = blockIdx.x * EPB + t;
    #pragma unroll
    for (int it = 0; it < EPT; ++it) {
        d[it] = dst[base + it * 256];
        s[it] = src[base + it * 256];
    }
    #pragma unroll
    for (int it = 0; it < EPT; ++it) atomicAdd(&lcnt[d[it] >> 7], 1);
    __syncthreads();
    for (int j = t; j < NB; j += 256) {
        int c = lcnt[j];
        lbase[j] = c ? atomicAdd(&gcur[j], c) : 0;
        lcnt[j] = 0;                // reuse as local cursor
    }
    __syncthreads();
    #pragma unroll
    for (int it = 0; it < EPT; ++it) {
        int b = d[it] >> 7;
        int slot = atomicAdd(&lcnt[b], 1);
        bucket[lbase[b] + slot] = ((unsigned)(d[it] & 127) << 17) | (unsigned)s[it];
    }
}

// Padded bucket slice -> node-ordered PADDED csr (same base b*CAPB, separate
// buffer), one block per bucket. Scatter confined to a 10KB LDS window;
// csr written coalesced. offs[n] = (global_start << 10) | deg  (packed).
// No compaction, no global scan needed.
__global__ __launch_bounds__(256) void bucket2csr_kernel(const unsigned* __restrict__ bucket,
                                                         const int* __restrict__ gcur,
                                                         unsigned* __restrict__ offs,
                                                         int* __restrict__ csr) {
    __shared__ int lcnt[BKT];
    __shared__ int ls[BKT];
    __shared__ int lcur[BKT];
    __shared__ int lcsr[CAP];
    int b = blockIdx.x;
    int t = threadIdx.x;
    int p0 = b * CAPB;                  // padded base (read AND write)
    int len = gcur[b] - p0;             // filled count
    if (t < BKT) lcnt[t] = 0;
    __syncthreads();
    for (int i = t; i < len; i += 256)
        atomicAdd(&lcnt[bucket[p0 + i] >> 17], 1);
    __syncthreads();
    if (t < BKT) ls[t] = lcnt[t];
    __syncthreads();
    #pragma unroll
    for (int off = 1; off < BKT; off <<= 1) {
        int u = (t < BKT && t >= off) ? ls[t - off] : 0;
        __syncthreads();
        if (t < BKT) ls[t] += u;
        __syncthreads();
    }
    if (t < BKT) {
        int ex = ls[t] - lcnt[t];       // exclusive, slice-local
        lcur[t] = ex;
        int n = b * BKT + t;
        if (n < NN) {
            unsigned dgc = (unsigned)(lcnt[t] > 1023 ? 1023 : lcnt[t]);
            offs[n] = ((unsigned)(p0 + ex) << 10) | dgc;
        }
    }
    __syncthreads();
    if (len <= CAP) {
        for (int i = t; i < len; i += 256) {
            unsigned pk = bucket[p0 + i];
            int pos = atomicAdd(&lcur[pk >> 17], 1);
            lcsr[pos] = (int)(pk & 0x1FFFFu);
        }
        __syncthreads();
        for (int i = t; i < len; i += 256) csr[p0 + i] = lcsr[i];
    } else {                             // statistically unreachable guard
        for (int i = t; i < len; i += 256) {
            unsigned pk = bucket[p0 + i];
            int pos = atomicAdd(&lcur[pk >> 17], 1);
            csr[p0 + pos] = (int)(pk & 0x1FFFFu);
        }
    }
}

// Fused per-step kernel: 8 threads per node = 4 edge-pairs x 2 row-halves.
// Each lane: ONE 16B gather (uint4 = 8 bf16 = half a row) per edge, 2-way
// unrolled. Merge pairs via shfl 2,4; exchange halves via shfl 1; 2 output
// columns per lane of the 16x16 matvec; Euler + pol renorm + stores.
// offs is packed (start<<10 | deg). xin != xout required.
__global__ __launch_bounds__(256) void step_kernel(const float2* __restrict__ x2in,
                                                   const uint4* __restrict__ xbin,
                                                   const unsigned* __restrict__ offs,
                                                   const int* __restrict__ csr,
                                                   const float* __restrict__ Wc,
                                                   const float* __restrict__ bc,
                                                   const float* __restrict__ b_out,
                                                   float2* __restrict__ x2out,
                                                   unsigned* __restrict__ xbout) {
    __shared__ float sWc[256];
    __shared__ float sbc[16];
    __shared__ float sb[16];
    int t = threadIdx.x;
    sWc[t] = Wc[t];
    if (t < 16) { sbc[t] = bc[t]; sb[t] = b_out[t]; }
    __syncthreads();

    int tid = blockIdx.x * 256 + t;
    int n = tid >> 3;
    int l = t & 7;                      // lane-in-node
    int p = l >> 1;                     // edge pair 0..3
    int hf = l & 1;                     // row half 0..1
    if (n >= NN) return;

    unsigned po = offs[n];
    int o0 = (int)(po >> 10);
    int deg = (int)(po & 1023u);
    int o1 = o0 + deg;

    float acc[8];
    #pragma unroll
    for (int j = 0; j < 8; ++j) acc[j] = 0.f;

    int e = o0 + p;
    // 2-way unrolled gather: both csr reads, then both 16B gathers, then adds.
    while (e + 4 < o1) {
        int s0 = csr[e];
        int s1 = csr[e + 4];
        uint4 v0 = xbin[s0 * 2 + hf];
        uint4 v1 = xbin[s1 * 2 + hf];
        acc[0] += blo(v0.x); acc[1] += bhi(v0.x);
        acc[2] += blo(v0.y); acc[3] += bhi(v0.y);
        acc[4] += blo(v0.z); acc[5] += bhi(v0.z);
        acc[6] += blo(v0.w); acc[7] += bhi(v0.w);
        acc[0] += blo(v1.x); acc[1] += bhi(v1.x);
        acc[2] += blo(v1.y); acc[3] += bhi(v1.y);
        acc[4] += blo(v1.z); acc[5] += bhi(v1.z);
        acc[6] += blo(v1.w); acc[7] += bhi(v1.w);
        e += 8;
    }
    if (e < o1) {
        int s0 = csr[e];
        uint4 v0 = xbin[s0 * 2 + hf];
        acc[0] += blo(v0.x); acc[1] += bhi(v0.x);
        acc[2] += blo(v0.y); acc[3] += bhi(v0.y);
        acc[4] += blo(v0.z); acc[5] += bhi(v0.z);
        acc[6] += blo(v0.w); acc[7] += bhi(v0.w);
    }

    // sum the 4 pairs (same hf lanes differ by xor 2, 4)
    #pragma unroll
    for (int j = 0; j < 8; ++j) {
        acc[j] += __shfl_xor(acc[j], 2);
        acc[j] += __shfl_xor(acc[j], 4);
    }
    // exchange halves (xor 1) -> full 16-dim aggregate, static indexing
    float a[16];
    #pragma unroll
    for (int j = 0; j < 8; ++j) {
        float oth = __shfl_xor(acc[j], 1);
        a[j]     = hf ? oth    : acc[j];
        a[8 + j] = hf ? acc[j] : oth;
    }

    float dg = (float)deg;

    // this lane's 2 output columns c0=2l, c0+1
    int c0 = 2 * l;
    float o0f = dg * sbc[c0] + sb[c0];
    float o1f = dg * sbc[c0 + 1] + sb[c0 + 1];
    #pragma unroll
    for (int k = 0; k < 16; ++k) {
        float ak = a[k];
        o0f = fmaf(ak, sWc[k * 16 + c0], o0f);
        o1f = fmaf(ak, sWc[k * 16 + c0 + 1], o1f);
    }

    float2 xv = x2in[(size_t)n * 8 + l];
    float xn0 = xv.x + DT_C * o0f;
    float xn1 = xv.y + DT_C * o1f;

    // pol renorm over cols 3..6
    bool in0 = (c0 >= 3 && c0 <= 6);
    bool in1 = (c0 + 1 >= 3 && c0 + 1 <= 6);
    float ssp = (in0 ? xn0 * xn0 : 0.f) + (in1 ? xn1 * xn1 : 0.f);
    ssp += __shfl_xor(ssp, 1);
    ssp += __shfl_xor(ssp, 2);
    ssp += __shfl_xor(ssp, 4);
    float sc = 1.0f / fmaxf(sqrtf(ssp), EPS_C);
    if (in0) xn0 *= sc;
    if (in1) xn1 *= sc;

    x2out[(size_t)n * 8 + l] = make_float2(xn0, xn1);
    xbout[(size_t)n * 8 + l] = (unsigned)f2b(xn0) | ((unsigned)f2b(xn1) << 16);
}

extern "C" void kernel_launch(void* const* d_in, const int* in_sizes, int n_in,
                              void* d_out, int out_size, void* d_ws, size_t ws_size,
                              hipStream_t stream) {
    const float* x0    = (const float*)d_in[0];
    const int*   ei    = (const int*)d_in[1];   // (2, NE): row0=src, row1=dst
    const float* W_msg = (const float*)d_in[2];
    const float* b_msg = (const float*)d_in[3];
    const float* W_out = (const float*)d_in[4];
    const float* b_out = (const float*)d_in[5];

    float* X = (float*)d_out;                   // final state buffer (ping-pong B1)

    // ws layout: Y (NN*16 f), xb0/xb1 (NN*8 u32), bucket (NB*CAPB u32),
    // csr (NB*CAPB int, padded), offs (NN u32 packed), gcur (NB), Wc, bc
    float*          Y      = (float*)d_ws;
    unsigned*       xb0    = (unsigned*)(Y + (size_t)NN * IN_DIM);      // NN*8 u32
    unsigned*       xb1    = xb0 + (size_t)NN * (IN_DIM / 2);
    unsigned*       bucket = xb1 + (size_t)NN * (IN_DIM / 2);
    int*            csr    = (int*)(bucket + (size_t)NB * CAPB);
    unsigned*       offs   = (unsigned*)(csr + (size_t)NB * CAPB);      // NN
    int*            gcur   = (int*)(offs + NN);                         // NB
    float*          Wc     = (float*)(gcur + NB);
    float*          bc     = Wc + 256;

    const int* src = ei;
    const int* dst = ei + NE;

    init_kernel<<<(NN * IN_DIM / 2 + 255) / 256, 256, 0, stream>>>(
        W_msg, b_msg, W_out, x0, Wc, bc, xb0, gcur);
    bucketA_kernel<<<NBB, 256, 0, stream>>>(src, dst, gcur, bucket);
    bucket2csr_kernel<<<NB, 256, 0, stream>>>(bucket, gcur, offs, csr);

    const int step_threads = NN * 8;
    const int step_blocks = (step_threads + 255) / 256;

    // 4 steps, ping-pong fp32: x0 -> Y -> X -> Y -> X ; bf16 shadow xb0<->xb1
    const float*    fin[4]  = { x0,  Y,   X,   Y  };
    float*          fout[4] = { Y,   X,   Y,   X  };
    const unsigned* bin[4]  = { xb0, xb1, xb0, xb1 };
    unsigned*       bout[4] = { xb1, xb0, xb1, xb0 };
    for (int s = 0; s < 4; ++s) {
        step_kernel<<<step_blocks, 256, 0, stream>>>(
            (const float2*)fin[s], (const uint4*)bin[s], offs, csr,
            Wc, bc, b_out, (float2*)fout[s], bout[s]);
    }
}

// Round 16
// 117.408 us; speedup vs baseline: 1.2617x; 1.0441x over previous
//
#include <hip/hip_runtime.h>

#define NN 100000
#define NE 1600000
#define IN_DIM 16
#define MSG_DIM 128
#define DT_C 0.1f
#define EPS_C 1e-8f
#define BKT 128                          // dst-nodes per bucket
#define NB ((NN + BKT - 1) / BKT)        // 782 buckets
#define EPB 2560                         // edges per bucketing block
#define NBB (NE / EPB)                   // 625 (exact)
#define EPT (EPB / 256)                  // 10 edges per thread
#define CAPB 4096                        // padded bucket region (mean 2048, 45 sigma)
#define CAP 2560                         // LDS csr-slice capacity in bucket2csr

__device__ __forceinline__ float blo(unsigned c) { return __uint_as_float(c << 16); }
__device__ __forceinline__ float bhi(unsigned c) { return __uint_as_float(c & 0xFFFF0000u); }
__device__ __forceinline__ unsigned short f2b(float f) {
    unsigned int i = __float_as_uint(f);
    unsigned int b = i + 0x7FFFu + ((i >> 16) & 1u);   // round-nearest-even
    return (unsigned short)(b >> 16);
}

// Fused init: Wc/bc (block 0); f32 -> bf16 shadow for xb0; zero dummy row NN
// in BOTH shadows; gcur padded-base init. One launch.
__global__ void init_kernel(const float* __restrict__ W_msg,
                            const float* __restrict__ b_msg,
                            const float* __restrict__ W_out,
                            const float* __restrict__ x,
                            float* __restrict__ Wc,
                            float* __restrict__ bc,
                            unsigned* __restrict__ xb0,
                            unsigned* __restrict__ xb1,
                            int* __restrict__ gcur) {
    int t = threadIdx.x;
    if (blockIdx.x == 0) {
        int i = t >> 4, j = t & 15;
        float s = 0.f;
        for (int k = 0; k < MSG_DIM; ++k)
            s += W_msg[i * MSG_DIM + k] * W_out[k * IN_DIM + j];
        Wc[t] = s;
        if (t < IN_DIM) {
            float sb = 0.f;
            for (int k = 0; k < MSG_DIM; ++k)
                sb += b_msg[k] * W_out[k * IN_DIM + t];
            bc[t] = sb;
        }
    }
    int i = blockIdx.x * blockDim.x + t;
    if (i < NB) gcur[i] = i * CAPB;
    if (i < NN * (IN_DIM / 2)) {
        float2 v = ((const float2*)x)[i];
        xb0[i] = (unsigned)f2b(v.x) | ((unsigned)f2b(v.y) << 16);
    } else if (i < (NN + 1) * (IN_DIM / 2)) {
        xb0[i] = 0u;                   // dummy row NN = zeros
        xb1[i] = 0u;
    }
}

// Bucketing pass into padded regions: partition edges by dst-bucket as packed
// (d_local<<17 | src). LDS per-bucket count, one global reserve atomic per
// (block,bucket), contiguous runs -> coalesced single edge-pass.
__global__ __launch_bounds__(256) void bucketA_kernel(const int* __restrict__ src,
                                                      const int* __restrict__ dst,
                                                      int* __restrict__ gcur,
                                                      unsigned* __restrict__ bucket) {
    __shared__ int lcnt[NB];
    __shared__ int lbase[NB];
    int t = threadIdx.x;
    for (int j = t; j < NB; j += 256) lcnt[j] = 0;
    __syncthreads();

    int d[EPT], s[EPT];
    int base = blockIdx.x * EPB + t;
    #pragma unroll
    for (int it = 0; it < EPT; ++it) {
        d[it] = dst[base + it * 256];
        s[it] = src[base + it * 256];
    }
    #pragma unroll
    for (int it = 0; it < EPT; ++it) atomicAdd(&lcnt[d[it] >> 7], 1);
    __syncthreads();
    for (int j = t; j < NB; j += 256) {
        int c = lcnt[j];
        lbase[j] = c ? atomicAdd(&gcur[j], c) : 0;
        lcnt[j] = 0;                // reuse as local cursor
    }
    __syncthreads();
    #pragma unroll
    for (int it = 0; it < EPT; ++it) {
        int b = d[it] >> 7;
        int slot = atomicAdd(&lcnt[b], 1);
        bucket[lbase[b] + slot] = ((unsigned)(d[it] & 127) << 17) | (unsigned)s[it];
    }
}

// Padded bucket slice -> node-ordered padded-EVEN csr (base b*CAPB), one
// block per bucket. Per-node lists start at even offsets and are padded to
// even length with dummy src=NN (zero row), so the step can read src pairs
// as int2. offs[n] = (start << 10) | true_deg.
__global__ __launch_bounds__(256) void bucket2csr_kernel(const unsigned* __restrict__ bucket,
                                                         const int* __restrict__ gcur,
                                                         unsigned* __restrict__ offs,
                                                         int* __restrict__ csr) {
    __shared__ int lcnt[BKT];
    __shared__ int ls[BKT];
    __shared__ int lcur[BKT];
    __shared__ int lcsr[CAP];
    int b = blockIdx.x;
    int t = threadIdx.x;
    int p0 = b * CAPB;                  // padded base (read AND write), even
    int len = gcur[b] - p0;             // filled count
    if (t < BKT) lcnt[t] = 0;
    __syncthreads();
    for (int i = t; i < len; i += 256)
        atomicAdd(&lcnt[bucket[p0 + i] >> 17], 1);
    __syncthreads();
    int pd = 0;
    if (t < BKT) { pd = lcnt[t] + (lcnt[t] & 1); ls[t] = pd; }
    __syncthreads();
    #pragma unroll
    for (int off = 1; off < BKT; off <<= 1) {
        int u = (t < BKT && t >= off) ? ls[t - off] : 0;
        __syncthreads();
        if (t < BKT) ls[t] += u;
        __syncthreads();
    }
    if (t < BKT) {
        int pex = ls[t] - pd;           // exclusive padded offset (even)
        lcur[t] = pex;
        int n = b * BKT + t;
        if (n < NN) {
            unsigned dgc = (unsigned)(lcnt[t] > 1023 ? 1023 : lcnt[t]);
            offs[n] = ((unsigned)(p0 + pex) << 10) | dgc;
        }
    }
    __syncthreads();
    int padtot = ls[BKT - 1];
    if (padtot <= CAP) {
        for (int i = t; i < len; i += 256) {
            unsigned pk = bucket[p0 + i];
            int pos = atomicAdd(&lcur[pk >> 17], 1);
            lcsr[pos] = (int)(pk & 0x1FFFFu);
        }
        __syncthreads();
        if (t < BKT && (lcnt[t] & 1)) lcsr[lcur[t]] = NN;   // pad slot
        __syncthreads();
        for (int i = t; i < padtot; i += 256) csr[p0 + i] = lcsr[i];
    } else {                             // statistically unreachable guard
        for (int i = t; i < len; i += 256) {
            unsigned pk = bucket[p0 + i];
            int pos = atomicAdd(&lcur[pk >> 17], 1);
            csr[p0 + pos] = (int)(pk & 0x1FFFFu);
        }
        __syncthreads();
        if (t < BKT && (lcnt[t] & 1)) csr[p0 + lcur[t]] = NN;
    }
}

// Fused per-step kernel, ALL-BF16 state: 8 threads per node = 4 edge-pairs x
// 2 row-halves. Per loop iter a lane reads ONE int2 (2 src ids) + TWO 16B
// bf16 half-row gathers. Own row = one u32 (exactly this lane's 2 columns).
// Merge pairs via shfl 2,4; halves via shfl 1; 2 output cols/lane; Euler +
// pol renorm. Steps 0..2 write bf16 shadow; final step writes fp32 d_out.
__global__ __launch_bounds__(256) void step_kernel(const uint4* __restrict__ xbin,
                                                   const unsigned* __restrict__ offs,
                                                   const int2* __restrict__ csr2,
                                                   const float* __restrict__ Wc,
                                                   const float* __restrict__ bc,
                                                   const float* __restrict__ b_out,
                                                   unsigned* __restrict__ xbout,
                                                   float2* __restrict__ x2out,
                                                   int last) {
    __shared__ float sWc[256];
    __shared__ float sbc[16];
    __shared__ float sb[16];
    int t = threadIdx.x;
    sWc[t] = Wc[t];
    if (t < 16) { sbc[t] = bc[t]; sb[t] = b_out[t]; }
    __syncthreads();

    int tid = blockIdx.x * 256 + t;
    int n = tid >> 3;
    int l = t & 7;                      // lane-in-node
    int p = l >> 1;                     // edge pair 0..3
    int hf = l & 1;                     // row half 0..1
    if (n >= NN) return;

    unsigned po = offs[n];
    int o0 = (int)(po >> 10);           // even
    int deg = (int)(po & 1023u);
    int pdeg = deg + (deg & 1);
    int e2beg = (o0 >> 1) + p;
    int e2end = (o0 + pdeg) >> 1;

    float acc[8];
    #pragma unroll
    for (int j = 0; j < 8; ++j) acc[j] = 0.f;

    for (int e2 = e2beg; e2 < e2end; e2 += 4) {
        int2 ss = csr2[e2];
        uint4 v0 = xbin[ss.x * 2 + hf];
        uint4 v1 = xbin[ss.y * 2 + hf];
        acc[0] += blo(v0.x); acc[1] += bhi(v0.x);
        acc[2] += blo(v0.y); acc[3] += bhi(v0.y);
        acc[4] += blo(v0.z); acc[5] += bhi(v0.z);
        acc[6] += blo(v0.w); acc[7] += bhi(v0.w);
        acc[0] += blo(v1.x); acc[1] += bhi(v1.x);
        acc[2] += blo(v1.y); acc[3] += bhi(v1.y);
        acc[4] += blo(v1.z); acc[5] += bhi(v1.z);
        acc[6] += blo(v1.w); acc[7] += bhi(v1.w);
    }

    // sum the 4 pairs (same hf lanes differ by xor 2, 4)
    #pragma unroll
    for (int j = 0; j < 8; ++j) {
        acc[j] += __shfl_xor(acc[j], 2);
        acc[j] += __shfl_xor(acc[j], 4);
    }
    // exchange halves (xor 1) -> full 16-dim aggregate, static indexing
    float a[16];
    #pragma unroll
    for (int j = 0; j < 8; ++j) {
        float oth = __shfl_xor(acc[j], 1);
        a[j]     = hf ? oth    : acc[j];
        a[8 + j] = hf ? acc[j] : oth;
    }

    float dg = (float)deg;

    // this lane's 2 output columns c0=2l, c0+1
    int c0 = 2 * l;
    float o0f = dg * sbc[c0] + sb[c0];
    float o1f = dg * sbc[c0 + 1] + sb[c0 + 1];
    #pragma unroll
    for (int k = 0; k < 16; ++k) {
        float ak = a[k];
        o0f = fmaf(ak, sWc[k * 16 + c0], o0f);
        o1f = fmaf(ak, sWc[k * 16 + c0 + 1], o1f);
    }

    // own row: one u32 = exactly this lane's 2 columns
    unsigned ox = ((const unsigned*)xbin)[(size_t)n * 8 + l];
    float xn0 = blo(ox) + DT_C * o0f;
    float xn1 = bhi(ox) + DT_C * o1f;

    // pol renorm over cols 3..6
    bool in0 = (c0 >= 3 && c0 <= 6);
    bool in1 = (c0 + 1 >= 3 && c0 + 1 <= 6);
    float ssp = (in0 ? xn0 * xn0 : 0.f) + (in1 ? xn1 * xn1 : 0.f);
    ssp += __shfl_xor(ssp, 1);
    ssp += __shfl_xor(ssp, 2);
    ssp += __shfl_xor(ssp, 4);
    float sc = 1.0f / fmaxf(sqrtf(ssp), EPS_C);
    if (in0) xn0 *= sc;
    if (in1) xn1 *= sc;

    if (last) {
        x2out[(size_t)n * 8 + l] = make_float2(xn0, xn1);
    } else {
        xbout[(size_t)n * 8 + l] = (unsigned)f2b(xn0) | ((unsigned)f2b(xn1) << 16);
    }
}

extern "C" void kernel_launch(void* const* d_in, const int* in_sizes, int n_in,
                              void* d_out, int out_size, void* d_ws, size_t ws_size,
                              hipStream_t stream) {
    const float* x0    = (const float*)d_in[0];
    const int*   ei    = (const int*)d_in[1];   // (2, NE): row0=src, row1=dst
    const float* W_msg = (const float*)d_in[2];
    const float* b_msg = (const float*)d_in[3];
    const float* W_out = (const float*)d_in[4];
    const float* b_out = (const float*)d_in[5];

    float* X = (float*)d_out;                   // fp32 final output only

    // ws layout: xb0/xb1 ((NN+1)*8 u32 each), bucket (NB*CAPB u32),
    // csr (NB*CAPB int), offs (NN u32 packed), gcur (NB), Wc, bc
    unsigned* xb0    = (unsigned*)d_ws;
    unsigned* xb1    = xb0 + (size_t)(NN + 1) * (IN_DIM / 2);
    unsigned* bucket = xb1 + (size_t)(NN + 1) * (IN_DIM / 2);
    int*      csr    = (int*)(bucket + (size_t)NB * CAPB);
    unsigned* offs   = (unsigned*)(csr + (size_t)NB * CAPB);            // NN
    int*      gcur   = (int*)(offs + NN);                               // NB
    float*    Wc     = (float*)(gcur + NB);
    float*    bc     = Wc + 256;

    const int* src = ei;
    const int* dst = ei + NE;

    init_kernel<<<((NN + 1) * (IN_DIM / 2) + 255) / 256, 256, 0, stream>>>(
        W_msg, b_msg, W_out, x0, Wc, bc, xb0, xb1, gcur);
    bucketA_kernel<<<NBB, 256, 0, stream>>>(src, dst, gcur, bucket);
    bucket2csr_kernel<<<NB, 256, 0, stream>>>(bucket, gcur, offs, csr);

    const int step_threads = NN * 8;
    const int step_blocks = (step_threads + 255) / 256;

    // 4 steps, bf16 ping-pong: xb0 -> xb1 -> xb0 -> xb1 -> fp32 X
    const unsigned* bin[4]  = { xb0, xb1, xb0, xb1 };
    unsigned*       bout[4] = { xb1, xb0, xb1, xb0 };
    for (int s = 0; s < 4; ++s) {
        step_kernel<<<step_blocks, 256, 0, stream>>>(
            (const uint4*)bin[s], offs, (const int2*)csr,
            Wc, bc, b_out, bout[s], (float2*)X, (s == 3) ? 1 : 0);
    }
}